// Round 15
// baseline (175.409 us; speedup 1.0000x reference)
//
#include <hip/hip_runtime.h>
#include <math.h>

// Fixed-point LeNet, B=2048. R24: co-pairing with NO address-taken arrays.
// R23 post-mortem: passed but 62->85us; WRITE +47MB / FETCH +21MB / VGPR=52
// = scratch spill. Cause: accA/accB passed BY POINTER into epilogue lambdas
// -> address escape defeats SROA -> arrays in scratch -> fence/unroll
// boundaries force spill/reload each iteration (R22 had the same bug).
// R24 = R23 with epilogues as MACROS (textual expansion, direct indexing)
// and the phase-B body inlined. Everything else identical: proven ws layout
// (27270 floats), 7xb128 weight loads, launch_bounds(256,4), cc-loop fence.
// Live set phase A ~96 regs < 128 cap. Bit-identical math to R21.
//
// Output layout (fp32, concatenated flat in reference return order):
//   logp[2048,10], conv1_in[2048,784], conv1_out[2048,5760],
//   conv2_in[2048,1440], conv2_out[2048,1280], fc1_in[2048,320],
//   fc1_out[2048,50], fc2_in[2048,50], fc2_out[2048,10]

#define NB 2048

#define OFF_LOGP   0
#define OFF_C1IN   (OFF_LOGP  + NB*10)
#define OFF_C1OUT  (OFF_C1IN  + NB*784)
#define OFF_C2IN   (OFF_C1OUT + NB*5760)
#define OFF_C2OUT  (OFF_C2IN  + NB*1440)
#define OFF_FC1IN  (OFF_C2OUT + NB*1280)
#define OFF_FC1OUT (OFF_FC1IN + NB*320)
#define OFF_FC2IN  (OFF_FC1OUT+ NB*50)
#define OFF_FC2OUT (OFF_FC2IN + NB*50)

#define MAGIC_F 12582912.0f   // 1.5 * 2^23

// Workspace layout (floats): pre-quantized weights, written by k0_prep.
// IDENTICAL to R17-R21 (proven; 27270 floats = 106.5 KB).
#define WS_WT1 0         // [320][64] transposed fw1 (j>=50 -> 0)
#define WS_B1  20480     // [64]
#define WS_WT2 20544     // [50][16] transposed fw2 (j>=10 -> 0)
#define WS_B2  21344     // [16]
#define WS_CW2 21360     // [20*10][28] padded conv2 rows, quant(w)*256 (col>=25 -> 0)
#define WS_CB2 26960     // [20] quant(b)*256
#define WS_CW1 26980     // [10][28] padded conv1 rows, quant(w)*256
#define WS_CB1 27260     // [10] quant(b)*256   (total 27270 floats)

__device__ __forceinline__ float clamp8(float v) {
    return __builtin_amdgcn_fmed3f(v, -8.0f, 7.0f);
}

// ---------------- K0: weight pre-quantization (52 small blocks) ----------------
__global__ __launch_bounds__(256)
void k0_prep(const float* __restrict__ cw1, const float* __restrict__ cb1,
             const float* __restrict__ cw2, const float* __restrict__ cb2,
             const float* __restrict__ fw1, const float* __restrict__ fb1,
             const float* __restrict__ fw2, const float* __restrict__ fb2,
             float* __restrict__ ws)
{
    const int t = threadIdx.x, b = blockIdx.x;
    if (b < 50) {
        // wT1 row j=b: coalesced read fw1[b*320 + i], scattered (cheap) write.
        const float* src = fw1 + b * 320;
        for (int i = t; i < 320; i += 256)
            ws[WS_WT1 + i * 64 + b] = clamp8(rintf(src[i] * 256.0f) * (1.0f / 256.0f));
    } else if (b == 50) {
        for (int idx = t; idx < 320 * 14; idx += 256) {     // zero cols 50..63
            int i = idx / 14, j = 50 + idx % 14;
            ws[WS_WT1 + i * 64 + j] = 0.0f;
        }
        for (int idx = t; idx < 800; idx += 256) {          // wT2[50][16]
            int k = idx >> 4, j = idx & 15;
            ws[WS_WT2 + idx] = (j < 10) ? clamp8(rintf(fw2[j * 50 + k] * 256.0f) * (1.0f / 256.0f)) : 0.0f;
        }
        if (t < 64) ws[WS_B1 + t] = (t < 50) ? clamp8(rintf(fb1[t] * 256.0f) * (1.0f / 256.0f)) : 0.0f;
        if (t < 16) ws[WS_B2 + t] = (t < 10) ? clamp8(rintf(fb2[t] * 256.0f) * (1.0f / 256.0f)) : 0.0f;
    } else {   // b == 51: conv weights, padded [rows][28], x256
        for (int idx = t; idx < 5600; idx += 256) {
            int cc = idx / 28, col = idx % 28;
            ws[WS_CW2 + idx] = (col < 25) ? rintf(cw2[cc * 25 + col] * 256.0f) : 0.0f;
        }
        if (t < 20) ws[WS_CB2 + t] = rintf(cb2[t] * 256.0f);
        for (int idx = t; idx < 280; idx += 256) {
            int cc = idx / 28, col = idx % 28;
            ws[WS_CW1 + idx] = (col < 25) ? rintf(cw1[cc * 25 + col] * 256.0f) : 0.0f;
        }
        if (t >= 32 && t < 42) ws[WS_CB1 + (t - 32)] = rintf(cb1[t - 32] * 256.0f);
    }
}

// Phase-A epilogue: direct array indexing, no address escape. Uses locals
// img, i, ii, jh, s_p1, out, ws from the enclosing scope.
#define EPI_A(CO, ACC) do {                                                       \
    const int co_ = (CO);                                                         \
    const float C_ = MAGIC_F - ws[WS_CB1 + co_];                                  \
    float v_[12];                                                                 \
    _Pragma("unroll")                                                             \
    for (int j = 0; j < 12; j++) v_[j] = (ACC[j] - C_) * (1.0f / 256.0f);         \
    float* gdst_ = out + OFF_C1OUT + (size_t)img * 5760 + co_ * 576 + i * 24 + 12 * jh; \
    _Pragma("unroll")                                                             \
    for (int k = 0; k < 3; k++) {                                                 \
        float4 st_ = { v_[4*k], v_[4*k+1], v_[4*k+2], v_[4*k+3] };                \
        *(float4*)(gdst_ + 4 * k) = st_;                                          \
    }                                                                             \
    float m_[6];                                                                  \
    _Pragma("unroll")                                                             \
    for (int j2 = 0; j2 < 6; j2++) m_[j2] = fmaxf(v_[2*j2], v_[2*j2+1]);          \
    float pm_[6];                                                                 \
    _Pragma("unroll")                                                             \
    for (int j2 = 0; j2 < 6; j2++) pm_[j2] = __shfl_xor(m_[j2], 2);               \
    if ((ii & 1) == 0) {                                                          \
        float pr_[6];                                                             \
        _Pragma("unroll")                                                         \
        for (int j2 = 0; j2 < 6; j2++)                                            \
            pr_[j2] = fmaxf(fmaxf(m_[j2], pm_[j2]), 0.0f);                        \
        const int o_ = co_ * 144 + (i >> 1) * 12 + 6 * jh;                        \
        float* g_ = out + OFF_C2IN + (size_t)img * 1440 + o_;                     \
        _Pragma("unroll")                                                         \
        for (int k = 0; k < 3; k++) {                                             \
            float2 st_ = { pr_[2*k], pr_[2*k+1] };                                \
            *(float2*)(g_ + 2 * k) = st_;                                         \
            *(float2*)(s_p1 + o_ + 2 * k) = st_;                                  \
        }                                                                         \
    }                                                                             \
} while (0)

// Phase-B epilogue: uses locals img, ch, i2, s_x, out, ws.
#define EPI_B(CO, ACC) do {                                                       \
    const int co_ = (CO);                                                         \
    float s_[8];                                                                  \
    _Pragma("unroll")                                                             \
    for (int j = 0; j < 8; j++) s_[j] = ACC[j] - MAGIC_F;                         \
    _Pragma("unroll")                                                             \
    for (int j = 0; j < 8; j++) s_[j] += __shfl_xor(s_[j], 1);                    \
    const float b2_ = ws[WS_CB2 + co_];                                           \
    float v_[8];                                                                  \
    _Pragma("unroll")                                                             \
    for (int j = 0; j < 8; j++) v_[j] = (s_[j] + b2_) * (1.0f / 256.0f);          \
    float m_[4], pm_[4];                                                          \
    _Pragma("unroll")                                                             \
    for (int c = 0; c < 4; c++) m_[c] = fmaxf(v_[2*c], v_[2*c+1]);                \
    _Pragma("unroll")                                                             \
    for (int c = 0; c < 4; c++) pm_[c] = __shfl_xor(m_[c], 2);                    \
    if (ch == 0) {                                                                \
        float4 st0_ = { v_[0], v_[1], v_[2], v_[3] };                             \
        float4 st1_ = { v_[4], v_[5], v_[6], v_[7] };                             \
        float* cdst_ = out + OFF_C2OUT + (size_t)img * 1280 + co_ * 64 + i2 * 8;  \
        *(float4*)(cdst_)     = st0_;                                             \
        *(float4*)(cdst_ + 4) = st1_;                                             \
        if ((i2 & 1) == 0) {                                                      \
            float4 pr_ = { fmaxf(fmaxf(m_[0], pm_[0]), 0.0f),                     \
                           fmaxf(fmaxf(m_[1], pm_[1]), 0.0f),                     \
                           fmaxf(fmaxf(m_[2], pm_[2]), 0.0f),                     \
                           fmaxf(fmaxf(m_[3], pm_[3]), 0.0f) };                   \
            const int o_ = co_ * 16 + (i2 >> 1) * 4;                              \
            *(float4*)(out + OFF_FC1IN + (size_t)img * 320 + o_) = pr_;           \
            float4 prc_ = { clamp8(pr_.x), clamp8(pr_.y), clamp8(pr_.z), clamp8(pr_.w) }; \
            *(float4*)(s_x + o_) = prc_;                                          \
        }                                                                         \
    }                                                                             \
} while (0)

// ---------------- K12W: whole net, FOUR waves per image, co-paired ----------------
// block=256 (4 waves), grid = NB = 2048.
// Phase A: lane (L<60): c5=L/12, r=L%12, ii=r>>1, jh=r&1, i=6wv+ii;
//   computes co=c5 AND c5+5 in one p-pass (x shared). Pool partner lane L^2.
// Phase B: groups g=t>>4 in 0..9 own co pair (g, g+10); ch=t&1, i2=(t>>1)&7;
//   reduce partner t^1, pool partner t^2. Groups 10..15 idle.
// Phase C: fc1+fc2+softmax on wave 0 (proven k3 body).
__global__ __launch_bounds__(256, 4)
void k12w(const float* __restrict__ x, const float* __restrict__ ws,
          float* __restrict__ out)
{
    __shared__ __align__(16) float s_x[784];    // image; [0..320) reused as fc1in
    __shared__ __align__(16) float s_p1[1440];  // pool1 out = conv2 in

    const int t   = threadIdx.x;
    const int img = blockIdx.x;
    const int wv  = t >> 6;
    const int L   = t & 63;

    {   // input staging: quantize once, write c1in + LDS
        const float* xg = x + (size_t)img * 784;
        float* c1in_g = out + OFF_C1IN + (size_t)img * 784;
        for (int i = t; i < 784; i += 256) {
            float v = rintf(xg[i] * 256.0f) * (1.0f / 256.0f);
            s_x[i] = v;
            c1in_g[i] = v;
        }
    }
    __syncthreads();

    // ================= phase A: conv1 + pool1, co-paired =================
    if (L < 60) {
        const int c5 = L / 12;         // 0..4
        const int r  = L % 12;
        const int ii = r >> 1;         // 0..5
        const int jh = r & 1;          // cols [12*jh, 12*jh+12)
        const int i  = wv * 6 + ii;    // 0..23

        float wregA[28], wregB[28];    // proven [*][28] 7xb128 pattern, x2 co
        {
            const float* wa = ws + WS_CW1 + c5 * 28;
            const float* wb = ws + WS_CW1 + (c5 + 5) * 28;
            #pragma unroll
            for (int k = 0; k < 7; k++) {
                float4 a4 = *(const float4*)(wa + 4 * k);
                float4 b4 = *(const float4*)(wb + 4 * k);
                wregA[4*k]=a4.x; wregA[4*k+1]=a4.y; wregA[4*k+2]=a4.z; wregA[4*k+3]=a4.w;
                wregB[4*k]=b4.x; wregB[4*k+1]=b4.y; wregB[4*k+2]=b4.z; wregB[4*k+3]=b4.w;
            }
        }

        float accA[12], accB[12];
        #pragma unroll
        for (int j = 0; j < 12; j++) { accA[j] = MAGIC_F; accB[j] = MAGIC_F; }

        #pragma unroll 1
        for (int p = 0; p < 5; p++) {
            float xr[16];              // per-p reload — small live range
            const float* row = s_x + (i + p) * 28 + 12 * jh;
            #pragma unroll
            for (int k = 0; k < 4; k++) {
                float4 v4 = *(const float4*)(row + 4 * k);
                xr[4*k] = v4.x; xr[4*k+1] = v4.y; xr[4*k+2] = v4.z; xr[4*k+3] = v4.w;
            }
            #pragma unroll
            for (int q = 0; q < 5; q++) {
                const float wA = wregA[p * 5 + q];
                const float wB = wregB[p * 5 + q];
                #pragma unroll
                for (int j = 0; j < 12; j++) {
                    accA[j] = fmaf(xr[q + j], wA, accA[j]);   // mul+round+add
                    accB[j] = fmaf(xr[q + j], wB, accB[j]);
                }
            }
        }

        EPI_A(c5, accA);
        EPI_A(c5 + 5, accB);
    }
    __syncthreads();   // s_p1 complete (all 10 ci)

    // ================= phase B: conv2 + pool2, co-paired (groups 0..9) =================
    if ((t >> 4) < 10) {
        const int g  = t >> 4;         // 0..9 -> co pair (g, g+10)
        const int ch = t & 1;          // ci-half
        const int i2 = (t >> 1) & 7;

        float accA[8], accB[8];
        #pragma unroll
        for (int j = 0; j < 8; j++) { accA[j] = MAGIC_F; accB[j] = MAGIC_F; }

        #pragma unroll 1
        for (int cc = 0; cc < 5; cc++) {
            asm volatile("" ::: "memory");   // proven-safe insurance vs load batching
            const int ci = ch * 5 + cc;

            float wregA[28], wregB[28];      // proven [cc][28] 7xb128 pattern, x2 co
            {
                const float* wa = ws + WS_CW2 + (g * 10 + ci) * 28;
                const float* wb = ws + WS_CW2 + ((g + 10) * 10 + ci) * 28;
                #pragma unroll
                for (int k = 0; k < 7; k++) {
                    float4 a4 = *(const float4*)(wa + 4 * k);
                    float4 b4 = *(const float4*)(wb + 4 * k);
                    wregA[4*k]=a4.x; wregA[4*k+1]=a4.y; wregA[4*k+2]=a4.z; wregA[4*k+3]=a4.w;
                    wregB[4*k]=b4.x; wregB[4*k+1]=b4.y; wregB[4*k+2]=b4.z; wregB[4*k+3]=b4.w;
                }
            }
            const float* xb = s_p1 + ci * 144;
            #pragma unroll
            for (int p = 0; p < 5; p++) {
                const float* row = xb + (i2 + p) * 12;
                float4 a4 = *(const float4*)(row);
                float4 b4 = *(const float4*)(row + 4);
                float4 c4 = *(const float4*)(row + 8);
                float xr[12] = { a4.x, a4.y, a4.z, a4.w, b4.x, b4.y, b4.z, b4.w,
                                 c4.x, c4.y, c4.z, c4.w };
                #pragma unroll
                for (int q = 0; q < 5; q++) {
                    const float wA = wregA[p * 5 + q];
                    const float wB = wregB[p * 5 + q];
                    #pragma unroll
                    for (int j = 0; j < 8; j++) {
                        accA[j] = fmaf(xr[q + j], wA, accA[j]);
                        accB[j] = fmaf(xr[q + j], wB, accB[j]);
                    }
                }
            }
        }

        EPI_B(g, accA);
        EPI_B(g + 10, accB);
    }
    __syncthreads();   // fc1in (s_x[0..320)) complete

    // ================= phase C: fc1 + fc2 + log_softmax (wave 0 only) =================
    if (wv == 0) {
        const float* sf = s_x;
        float acc = ws[WS_B1 + L];
        #pragma unroll 8
        for (int k = 0; k < 320; k++)
            acc = fmaf(sf[k], ws[WS_WT1 + k * 64 + L], acc);   // LDS broadcast + 256B coalesced
        float o1 = rintf(clamp8(acc) * 256.0f) * (1.0f / 256.0f);
        float r1 = fmaxf(o1, 0.0f);
        if (L < 50) {
            out[OFF_FC1OUT + (size_t)img * 50 + L] = o1;
            out[OFF_FC2IN  + (size_t)img * 50 + L] = r1;
        }
        float yc = clamp8(r1);                 // valid on lanes 0..49

        float acc2 = ws[WS_B2 + (L & 15)];
        #pragma unroll 10
        for (int k = 0; k < 50; k++) {
            float yk = __shfl(yc, k);
            acc2 = fmaf(yk, ws[WS_WT2 + k * 16 + (L & 15)], acc2);
        }
        float o2 = rintf(clamp8(acc2) * 256.0f) * (1.0f / 256.0f);
        if (L < 10) out[OFF_FC2OUT + (size_t)img * 10 + L] = o2;

        float vmx = (L < 10) ? o2 : -3.0e38f;
        #pragma unroll
        for (int d = 1; d < 16; d <<= 1)
            vmx = fmaxf(vmx, __shfl_xor(vmx, d, 16));
        float e = (L < 10) ? expf(o2 - vmx) : 0.0f;
        #pragma unroll
        for (int d = 1; d < 16; d <<= 1)
            e += __shfl_xor(e, d, 16);
        float lse = vmx + logf(e);
        if (L < 10) out[OFF_LOGP + (size_t)img * 10 + L] = o2 - lse;
    }
}

extern "C" void kernel_launch(void* const* d_in, const int* in_sizes, int n_in,
                              void* d_out, int out_size, void* d_ws, size_t ws_size,
                              hipStream_t stream) {
    const float* x   = (const float*)d_in[0];
    const float* cw1 = (const float*)d_in[1];
    const float* cb1 = (const float*)d_in[2];
    const float* cw2 = (const float*)d_in[3];
    const float* cb2 = (const float*)d_in[4];
    const float* fw1 = (const float*)d_in[5];
    const float* fb1 = (const float*)d_in[6];
    const float* fw2 = (const float*)d_in[7];
    const float* fb2 = (const float*)d_in[8];
    float* o  = (float*)d_out;
    float* ws = (float*)d_ws;

    k0_prep<<<52, 256, 0, stream>>>(cw1, cb1, cw2, cb2, fw1, fb1, fw2, fb2, ws);
    k12w   <<<NB, 256, 0, stream>>>(x, ws, o);
}